// Round 4
// baseline (88.239 us; speedup 1.0000x reference)
//
#include <hip/hip_runtime.h>
#include <math.h>

// Problem constants (from reference): B=8, C=32, F=32, K=3, H=W=32
#define NB 8
#define NC 32
#define NF 32
#define NH 32
#define NW 32
#define NQ 9
#define CSPLIT 4            // channel-loop split factor (8 channels per block)
#define CPB (NC / CSPLIT)   // channels per block

#define PROWS 34            // padded rows
#define PCOLS 36            // padded cols (+2 slack so rows stay 16B-aligned
                            //  and xx=31's dwordx4 overread stays in-bounds)

// d_ws layout (floats):
//   [0, COEFF_FLOATS)                : coeff records, 12 floats per (f,q,c)
//   [COEFF_FLOATS, +XPAD_FLOATS)     : zero-padded input [B][C][34][36]
#define NREC (NF * NQ * NC)                    // 9216 records
#define COEFF_FLOATS (NREC * 12)               // 110592  (x4 bytes: 16B-aligned)
#define XPAD_FLOATS (NB * NC * PROWS * PCOLS)  // 313344

typedef float f4 __attribute__((ext_vector_type(4), aligned(4)));

// --- prep kernel 1: interleave nums/denoms into 48B records -----------------
// record r=(f*9+q)*32+c : [a0..a3][d0..d3][a4,a5,pad,pad]
__global__ __launch_bounds__(256) void reformat_coeffs(
    const float* __restrict__ nums, const float* __restrict__ dens,
    float* __restrict__ rec)
{
    int r = blockIdx.x * 256 + threadIdx.x;
    if (r >= NREC) return;
    const float* a = nums + (size_t)r * 6;
    const float* d = dens + (size_t)r * 4;
    float* o = rec + (size_t)r * 12;
    o[0] = a[0]; o[1] = a[1]; o[2]  = a[2]; o[3]  = a[3];
    o[4] = d[0]; o[5] = d[1]; o[6]  = d[2]; o[7]  = d[3];
    o[8] = a[4]; o[9] = a[5]; o[10] = 0.f;  o[11] = 0.f;
}

// --- prep kernel 2: zero-padded copy of x -----------------------------------
__global__ __launch_bounds__(256) void prepad_x(
    const float* __restrict__ x, float* __restrict__ xp)
{
    int idx = blockIdx.x * 256 + threadIdx.x; // < XPAD_FLOATS exactly
    int px  = idx % PCOLS;
    int t1  = idx / PCOLS;
    int py  = t1 % PROWS;
    int bc  = t1 / PROWS;
    float v = 0.f;
    if (py >= 1 && py <= NH && px >= 1 && px <= NW)
        v = x[(size_t)bc * NH * NW + (py - 1) * NW + (px - 1)];
    xp[idx] = v;
}

// --- main kernel -------------------------------------------------------------
// Block = 256 threads, 2 vertically-adjacent pixels each (half image).
// Grid = B*F*2*CSPLIT = 2048 -> 8 blocks/CU -> 32 waves/CU (8/SIMD).
// NO LDS, NO barriers: window loads are vmcnt-only (pipelined one channel
// ahead); coefficient loads are pure-SMEM lgkmcnt (2 aligned s_loads per
// (q,c)). Waves desynchronize so scalar-load latency overlaps across waves.
__global__ __launch_bounds__(256, 8) void ka_conv_rational_kernel(
    const float* __restrict__ cf,   // coeff records [NREC][12]
    const float* __restrict__ xp,   // padded input [B][C][34][36]
    float* __restrict__ out)        // [B, F, H, W] (pre-zeroed)
{
    const int t    = threadIdx.x;
    const int bid  = blockIdx.x;          // 0..2047
    const int cs   = bid & (CSPLIT - 1);
    const int half = (bid >> 2) & 1;
    const int bf   = bid >> 3;            // b*NF + f
    const int f    = bf & (NF - 1);
    const int bb   = bf >> 5;
    const int xx   = t & 31;              // output col
    const int ty   = t >> 5;              // 0..7
    const int y0   = half * 16 + ty * 2;  // output row of px0 (= padded top row)
    const int c0   = cs * CPB;

    // window base: padded rows y0..y0+3, padded cols xx..xx+3 (cols xx..xx+2 used)
    const float* xbase = xp + (((size_t)(bb * NC + c0) * PROWS) + y0) * PCOLS + xx;
    const float* cfb   = cf + (size_t)(f * NQ * NC + c0) * 12;

    f4 cur[4], nxt[4];
#pragma unroll
    for (int r = 0; r < 4; ++r)
        cur[r] = *(const f4*)(xbase + r * PCOLS);

    float acc0 = 0.f, acc1 = 0.f;

    for (int ci = 0; ci < CPB; ++ci) {
        // prefetch next channel's window rows (vmcnt hides behind q-loop)
        if (ci + 1 < CPB) {
            const float* xn = xbase + (size_t)(ci + 1) * PROWS * PCOLS;
#pragma unroll
            for (int r = 0; r < 4; ++r)
                nxt[r] = *(const f4*)(xn + r * PCOLS);
        }

#pragma unroll
        for (int q = 0; q < NQ; ++q) {
            // block-uniform record -> s_load_dwordx8 + s_load_dwordx2
            const float* rp = cfb + (size_t)(q * NC + ci) * 12;
            const float a0 = rp[0], a1 = rp[1], a2 = rp[2], a3 = rp[3];
            const float d0 = rp[4], d1 = rp[5], d2 = rp[6], d3 = rp[7];
            const float a4 = rp[8], a5 = rp[9];
            const int qi = q / 3, qj = q - qi * 3;

            {
                const float w  = cur[qi][qj];
                float nu = fmaf(fmaf(fmaf(fmaf(fmaf(a5, w, a4), w, a3), w, a2), w, a1), w, a0);
                float dp = fmaf(fmaf(fmaf(d3, w, d2), w, d1), w, d0) * w;
                float de = 1.0f + fabsf(dp);
                acc0 = fmaf(nu, __builtin_amdgcn_rcpf(de), acc0);
            }
            {
                const float w  = cur[qi + 1][qj];
                float nu = fmaf(fmaf(fmaf(fmaf(fmaf(a5, w, a4), w, a3), w, a2), w, a1), w, a0);
                float dp = fmaf(fmaf(fmaf(d3, w, d2), w, d1), w, d0) * w;
                float de = 1.0f + fabsf(dp);
                acc1 = fmaf(nu, __builtin_amdgcn_rcpf(de), acc1);
            }
        }

#pragma unroll
        for (int r = 0; r < 4; ++r)
            cur[r] = nxt[r];
    }

    float* op = out + ((size_t)bf * NH + y0) * NW + xx;
    unsafeAtomicAdd(op,      acc0);
    unsafeAtomicAdd(op + NW, acc1);
}

extern "C" void kernel_launch(void* const* d_in, const int* in_sizes, int n_in,
                              void* d_out, int out_size, void* d_ws, size_t ws_size,
                              hipStream_t stream) {
    const float* x    = (const float*)d_in[0];
    const float* nums = (const float*)d_in[1];
    const float* dens = (const float*)d_in[2];
    float* out = (float*)d_out;

    float* cf = (float*)d_ws;                 // 442368 B, 16B-aligned
    float* xpad = cf + COEFF_FLOATS;          // offset 442368 B (16B-aligned)

    // prep (stream-ordered; dispatch boundaries give cross-XCD visibility)
    reformat_coeffs<<<(NREC + 255) / 256, 256, 0, stream>>>(nums, dens, cf);
    prepad_x<<<XPAD_FLOATS / 256, 256, 0, stream>>>(x, xpad);

    // atomic accumulation target must start at zero (harness poisons d_out)
    hipMemsetAsync(d_out, 0, (size_t)out_size * sizeof(float), stream);

    dim3 grid(NB * NF * 2 * CSPLIT); // 2048 blocks: (b, f, half, csplit)
    ka_conv_rational_kernel<<<grid, 256, 0, stream>>>(cf, xpad, out);
}